// Round 8
// baseline (257.650 us; speedup 1.0000x reference)
//
#include <hip/hip_runtime.h>

#define NG 16
#define NC 4
#define BPB 8      // batch items per block
#define TSTEPS 8
#define PITCH 34   // float4 per (c,y) row: 16 x * 2 slots + 2 pad
#define CROW (NG * PITCH)   // 544 float4 per channel

__device__ __forceinline__ void fma8(float w, const float4& s0, const float4& s1,
                                     float4& a0, float4& a1) {
    a0.x = fmaf(w, s0.x, a0.x);
    a0.y = fmaf(w, s0.y, a0.y);
    a0.z = fmaf(w, s0.z, a0.z);
    a0.w = fmaf(w, s0.w, a0.w);
    a1.x = fmaf(w, s1.x, a1.x);
    a1.y = fmaf(w, s1.y, a1.y);
    a1.z = fmaf(w, s1.z, a1.z);
    a1.w = fmaf(w, s1.w, a1.w);
}

__device__ __forceinline__ float4 lrelu4(float4 v) {
    float4 r;
    r.x = v.x > 0.f ? v.x : 0.1f * v.x;
    r.y = v.y > 0.f ? v.y : 0.1f * v.y;
    r.z = v.z > 0.f ? v.z : 0.1f * v.z;
    r.w = v.w > 0.f ? v.w : 0.1f * v.w;
    return r;
}

// Wt[(c*25+u*5+v)*256 + pix] : float4 over o, OOB (u,v) pre-zeroed.
// Original W: [y][x][o][c][u][v] (flat: pix*400 + o*100 + c*25 + u*5 + v)
__global__ void wt_transpose(const float* __restrict__ W, float4* __restrict__ Wt) {
    int t = blockIdx.x * 256 + threadIdx.x;   // 0..25599
    if (t >= 25600) return;
    int r = t >> 8;            // c*25 + u*5 + v
    int pix = t & 255;
    int c = r / 25, uv = r - c * 25, u = uv / 5, v = uv - u * 5;
    int y = pix >> 4, x = pix & 15;
    float4 w = make_float4(0.f, 0.f, 0.f, 0.f);
    if ((unsigned)(y + u - 2) < 16u && (unsigned)(x + v - 2) < 16u) {
        int base = pix * 400 + c * 25 + uv;
        w.x = W[base];
        w.y = W[base + 100];
        w.z = W[base + 200];
        w.w = W[base + 300];
    }
    Wt[r * 256 + pix] = w;
}

// Thread = pixel; owns all 4 output channels for 8 batch items.
// SINGLE-buffered state LDS (2 barriers/step), pitch-34 rows + slot swizzle
// (conflict-free b128), 34816 B -> 4 blocks/CU = 4 waves/SIMD.
// Weights: distance-1 register double-buffer (2 x 5 float4 = 40 VGPR) inside
// a RUNTIME g-loop (g += 2; 10 static chunks/body, phase-invariant) — the
// runtime loop fences scheduler load-hoisting (R4-proven); fully-unrolled
// bodies spilled 3 GB to scratch in R3/R5/R6.
__global__ __launch_bounds__(256, 4)
void reservoir_kernel(const float* __restrict__ X, const float4* __restrict__ Wt,
                      float* __restrict__ out, int batch) {
    __shared__ float4 smv[NC * CROW];   // 34816 B
    float* smf = reinterpret_cast<float*>(smv);

    const int tid = threadIdx.x;        // pixel index
    const int y = tid >> 4;
    const int x = tid & 15;
    const long itemBase = (long)blockIdx.x * BPB;

    const float4* Wp = Wt + tid;

    // ---- weight pipeline registers: 2 buffers x 5 float4, named ----
    float4 b0_0, b0_1, b0_2, b0_3, b0_4;
    float4 b1_0, b1_1, b1_2, b1_3, b1_4;

#define LOADBUF(B, OFF) \
    B##_0 = Wp[(OFF)]; \
    B##_1 = Wp[(OFF) + 256]; \
    B##_2 = Wp[(OFF) + 512]; \
    B##_3 = Wp[(OFF) + 768]; \
    B##_4 = Wp[(OFF) + 1024];

    // prologue: chunk 0 -> buffer 0
    LOADBUF(b0, 0)

    // ---- init: X (first 784 of 1024 slots) -> LDS (nontemporal) ----
    for (int b = 0; b < BPB; ++b) {
        long item = itemBase + b;
        const float* xr = X + item * 784;
        const int g = b >> 2, j = b & 3;
        #pragma unroll
        for (int kk = 0; kk < 4; ++kk) {
            int idx = tid + kk * 256;
            float v = 0.f;
            if (idx < 784 && item < batch) v = __builtin_nontemporal_load(&xr[idx]);
            int c = idx >> 8, rem = idx & 255, yy = rem >> 4, xx = rem & 15;
            int phys = g ^ ((xx >> 2) & 1);
            smf[((c * NG + yy) * PITCH + xx * 2 + phys) * 4 + j] = v;
        }
    }

    int ybf[5], xbf[5];
    #pragma unroll
    for (int u = 0; u < 5; ++u) {
        int yy = y + u - 2;
        yy = yy < 0 ? 0 : (yy > 15 ? 15 : yy);
        ybf[u] = yy * PITCH;
    }
    #pragma unroll
    for (int v = 0; v < 5; ++v) {
        int xv = x + v - 2;
        xv = xv < 0 ? 0 : (xv > 15 ? 15 : xv);
        xbf[v] = xv * 2 + ((xv >> 2) & 1);    // phys slot-0 offset
    }
    const int swx = (x >> 2) & 1;
    const int pa = y * PITCH + x * 2;

    __syncthreads();

#define FMA_V(WV, V) { \
    const int i0 = sbase + xbf[V]; \
    const float4 s0 = smv[i0]; \
    const float4 s1 = smv[i0 ^ 1]; \
    fma8(WV.x, s0, s1, a00, a01); \
    fma8(WV.y, s0, s1, a10, a11); \
    fma8(WV.z, s0, s1, a20, a21); \
    fma8(WV.w, s0, s1, a30, a31); }

#define FMA5(B) FMA_V(B##_0, 0) FMA_V(B##_1, 1) FMA_V(B##_2, 2) FMA_V(B##_3, 3) FMA_V(B##_4, 4)

    // consume b0 (even chunk), prefetch next chunk into b1 — and vice versa
#define CH_A(CB, U, POFF) \
    LOADBUF(b1, POFF) \
    { const int sbase = (CB) + ybf[U]; FMA5(b0) }
#define CH_B(CB, U, POFF) \
    LOADBUF(b0, POFF) \
    { const int sbase = (CB) + ybf[U]; FMA5(b1) }

    #pragma unroll 1
    for (int t = 0; t < TSTEPS; ++t) {
        float4 a00 = {0,0,0,0}, a01 = {0,0,0,0};
        float4 a10 = {0,0,0,0}, a11 = {0,0,0,0};
        float4 a20 = {0,0,0,0}, a21 = {0,0,0,0};
        float4 a30 = {0,0,0,0}, a31 = {0,0,0,0};

        #pragma unroll 1
        for (int g = 0; g < 4; g += 2) {    // chunk k = c*5+u at Wp f4 off k*1280
            const int cb0 = g * CROW;       // c = g
            const int cb1 = cb0 + CROW;     // c = g+1
            const int wo = g * 6400;
            const int wlast = (g == 2) ? 0 : wo + 12800;  // wrap to chunk 0

            CH_A(cb0, 0, wo + 1280)
            CH_B(cb0, 1, wo + 2560)
            CH_A(cb0, 2, wo + 3840)
            CH_B(cb0, 3, wo + 5120)
            CH_A(cb0, 4, wo + 6400)
            CH_B(cb1, 0, wo + 7680)
            CH_A(cb1, 1, wo + 8960)
            CH_B(cb1, 2, wo + 10240)
            CH_A(cb1, 3, wo + 11520)
            CH_B(cb1, 4, wlast)
        }

        a00 = lrelu4(a00); a01 = lrelu4(a01);
        a10 = lrelu4(a10); a11 = lrelu4(a11);
        a20 = lrelu4(a20); a21 = lrelu4(a21);
        a30 = lrelu4(a30); a31 = lrelu4(a31);

        if (t < TSTEPS - 1) {
            __syncthreads();   // all reads of S[t] complete before overwrite
            int c0 = 0 * CROW + pa;
            smv[c0 + swx] = a00; smv[c0 + (swx ^ 1)] = a01;
            int c1 = 1 * CROW + pa;
            smv[c1 + swx] = a10; smv[c1 + (swx ^ 1)] = a11;
            int c2 = 2 * CROW + pa;
            smv[c2 + swx] = a20; smv[c2 + (swx ^ 1)] = a21;
            int c3 = 3 * CROW + pa;
            smv[c3 + swx] = a30; smv[c3 + (swx ^ 1)] = a31;
            __syncthreads();   // writes visible before next read phase
        } else {
            float4 p0, p1;
            p0.x = (a00.x + a10.x + a20.x + a30.x) * 0.25f;
            p0.y = (a00.y + a10.y + a20.y + a30.y) * 0.25f;
            p0.z = (a00.z + a10.z + a20.z + a30.z) * 0.25f;
            p0.w = (a00.w + a10.w + a20.w + a30.w) * 0.25f;
            p1.x = (a01.x + a11.x + a21.x + a31.x) * 0.25f;
            p1.y = (a01.y + a11.y + a21.y + a31.y) * 0.25f;
            p1.z = (a01.z + a11.z + a21.z + a31.z) * 0.25f;
            p1.w = (a01.w + a11.w + a21.w + a31.w) * 0.25f;
            long ob = itemBase * 256 + tid;
            if (itemBase + 0 < batch) __builtin_nontemporal_store(p0.x, &out[ob + 0 * 256]);
            if (itemBase + 1 < batch) __builtin_nontemporal_store(p0.y, &out[ob + 1 * 256]);
            if (itemBase + 2 < batch) __builtin_nontemporal_store(p0.z, &out[ob + 2 * 256]);
            if (itemBase + 3 < batch) __builtin_nontemporal_store(p0.w, &out[ob + 3 * 256]);
            if (itemBase + 4 < batch) __builtin_nontemporal_store(p1.x, &out[ob + 4 * 256]);
            if (itemBase + 5 < batch) __builtin_nontemporal_store(p1.y, &out[ob + 5 * 256]);
            if (itemBase + 6 < batch) __builtin_nontemporal_store(p1.z, &out[ob + 6 * 256]);
            if (itemBase + 7 < batch) __builtin_nontemporal_store(p1.w, &out[ob + 7 * 256]);
        }
    }
}

extern "C" void kernel_launch(void* const* d_in, const int* in_sizes, int n_in,
                              void* d_out, int out_size, void* d_ws, size_t ws_size,
                              hipStream_t stream) {
    const float* X = (const float*)d_in[0];
    const float* W = (const float*)d_in[1];
    float* out = (float*)d_out;
    const int batch = in_sizes[0] / 784;            // 8192
    const int blocks = (batch + BPB - 1) / BPB;     // 1024

    wt_transpose<<<100, 256, 0, stream>>>(W, (float4*)d_ws);
    reservoir_kernel<<<blocks, 256, 0, stream>>>(
        X, (const float4*)d_ws, out, batch);
}

// Round 9
// 235.794 us; speedup vs baseline: 1.0927x; 1.0927x over previous
//
#include <hip/hip_runtime.h>

#define NG 16
#define NC 4
#define BPB 8      // batch items per block
#define TSTEPS 8
#define PITCH 34   // float4 per (c,y) row: 16 x * 2 slots + 2 pad
#define CROW (NG * PITCH)   // 544 float4 per channel

__device__ __forceinline__ void fma8(float w, const float4& s0, const float4& s1,
                                     float4& a0, float4& a1) {
    a0.x = fmaf(w, s0.x, a0.x);
    a0.y = fmaf(w, s0.y, a0.y);
    a0.z = fmaf(w, s0.z, a0.z);
    a0.w = fmaf(w, s0.w, a0.w);
    a1.x = fmaf(w, s1.x, a1.x);
    a1.y = fmaf(w, s1.y, a1.y);
    a1.z = fmaf(w, s1.z, a1.z);
    a1.w = fmaf(w, s1.w, a1.w);
}

__device__ __forceinline__ float4 lrelu4(float4 v) {
    float4 r;
    r.x = fmaxf(v.x, 0.1f * v.x);
    r.y = fmaxf(v.y, 0.1f * v.y);
    r.z = fmaxf(v.z, 0.1f * v.z);
    r.w = fmaxf(v.w, 0.1f * v.w);
    return r;
}

// DPP row shift: CTRL 0x101..0x10F = row_shl:N (lane i <- lane i+N within its
// 16-lane row), 0x111..0x11F = row_shr:N (lane i <- lane i-N). bound_ctrl=1:
// shifted-in lanes read 0 -- matches the reference's zero padding at x edges
// (and the corresponding weights are pre-zeroed anyway).
template<int CTRL>
__device__ __forceinline__ float dppf(float x) {
    return __int_as_float(__builtin_amdgcn_update_dpp(
        0, __float_as_int(x), CTRL, 0xF, 0xF, true));
}
template<int CTRL>
__device__ __forceinline__ float4 dpp4(float4 v) {
    float4 r;
    r.x = dppf<CTRL>(v.x);
    r.y = dppf<CTRL>(v.y);
    r.z = dppf<CTRL>(v.z);
    r.w = dppf<CTRL>(v.w);
    return r;
}

// Wt[(c*25+u*5+v)*256 + pix] : float4 over o, OOB (u,v) pre-zeroed.
// Original W: [y][x][o][c][u][v] (flat: pix*400 + o*100 + c*25 + u*5 + v)
__global__ void wt_transpose(const float* __restrict__ W, float4* __restrict__ Wt) {
    int t = blockIdx.x * 256 + threadIdx.x;   // 0..25599
    if (t >= 25600) return;
    int r = t >> 8;            // c*25 + u*5 + v
    int pix = t & 255;
    int c = r / 25, uv = r - c * 25, u = uv / 5, v = uv - u * 5;
    int y = pix >> 4, x = pix & 15;
    float4 w = make_float4(0.f, 0.f, 0.f, 0.f);
    if ((unsigned)(y + u - 2) < 16u && (unsigned)(x + v - 2) < 16u) {
        int base = pix * 400 + c * 25 + uv;
        w.x = W[base];
        w.y = W[base + 100];
        w.z = W[base + 200];
        w.w = W[base + 300];
    }
    Wt[r * 256 + pix] = w;
}

// Thread = pixel; owns all 4 output channels for 8 batch items.
// Wave = 4 grid rows x 16 x -> the 5 x-taps are DPP row-neighbors:
// per (c,u) each thread LDS-reads only its OWN pixel (2 b128 instead of 10);
// x+/-1, x+/-2 taps come from v_mov_dpp row_shl/shr (zero-fill at row edges).
// LDS reads/step: 40 b128 (was 200). Single-buffered state, pitch-34 + slot
// swizzle, 34816 B -> 4 blocks/CU. Weights: distance-1 register double-buffer
// inside a runtime g-loop (fences scheduler load-hoisting; R4/R8-proven).
// waves_per_eu(4,4): LDS caps at 4 waves/EU, so pin the allocator at the
// 128-VGPR budget (R8 squeezed to 64 and leaked ~90 MB scratch writes).
__global__ __launch_bounds__(256, 4)
__attribute__((amdgpu_waves_per_eu(4, 4)))
void reservoir_kernel(const float* __restrict__ X, const float4* __restrict__ Wt,
                      float* __restrict__ out, int batch) {
    __shared__ float4 smv[NC * CROW];   // 34816 B
    float* smf = reinterpret_cast<float*>(smv);

    const int tid = threadIdx.x;        // pixel index
    const int y = tid >> 4;
    const int x = tid & 15;
    const long itemBase = (long)blockIdx.x * BPB;

    const float4* Wp = Wt + tid;

    // ---- weight pipeline registers: 2 buffers x 5 float4, named ----
    float4 b0_0, b0_1, b0_2, b0_3, b0_4;
    float4 b1_0, b1_1, b1_2, b1_3, b1_4;

#define LOADBUF(B, OFF) \
    B##_0 = Wp[(OFF)]; \
    B##_1 = Wp[(OFF) + 256]; \
    B##_2 = Wp[(OFF) + 512]; \
    B##_3 = Wp[(OFF) + 768]; \
    B##_4 = Wp[(OFF) + 1024];

    // prologue: chunk 0 -> buffer 0
    LOADBUF(b0, 0)

    // ---- init: X (first 784 of 1024 slots) -> LDS (nontemporal) ----
    for (int b = 0; b < BPB; ++b) {
        long item = itemBase + b;
        const float* xr = X + item * 784;
        const int g = b >> 2, j = b & 3;
        #pragma unroll
        for (int kk = 0; kk < 4; ++kk) {
            int idx = tid + kk * 256;
            float v = 0.f;
            if (idx < 784 && item < batch) v = __builtin_nontemporal_load(&xr[idx]);
            int c = idx >> 8, rem = idx & 255, yy = rem >> 4, xx = rem & 15;
            int phys = g ^ ((xx >> 2) & 1);
            smf[((c * NG + yy) * PITCH + xx * 2 + phys) * 4 + j] = v;
        }
    }

    int ybf[5];
    #pragma unroll
    for (int u = 0; u < 5; ++u) {
        int yy = y + u - 2;
        yy = yy < 0 ? 0 : (yy > 15 ? 15 : yy);   // OOB rows: weights are zero
        ybf[u] = yy * PITCH;
    }
    const int swx = (x >> 2) & 1;
    const int xown = x * 2 + swx;       // phys slot-0 f4 offset of own pixel
    const int pa = y * PITCH + x * 2;

    __syncthreads();

    // per (c,u): read own 8 floats once; DPP-shift for the 4 off-center taps.
    // B##_V holds w[v=V] (float4 over o). v=2 centered; v=1/0 from lane x-1/x-2
    // (row_shr 0x111/0x112); v=3/4 from lane x+1/x+2 (row_shl 0x101/0x102).
#define CHUNK_DPP(B, CB, U) { \
    const int i0 = (CB) + ybf[U] + xown; \
    const float4 s0 = smv[i0]; \
    const float4 s1 = smv[i0 ^ 1]; \
    fma8(B##_2.x, s0, s1, a00, a01); \
    fma8(B##_2.y, s0, s1, a10, a11); \
    fma8(B##_2.z, s0, s1, a20, a21); \
    fma8(B##_2.w, s0, s1, a30, a31); \
    { const float4 t0 = dpp4<0x111>(s0), t1 = dpp4<0x111>(s1); \
      fma8(B##_1.x, t0, t1, a00, a01); \
      fma8(B##_1.y, t0, t1, a10, a11); \
      fma8(B##_1.z, t0, t1, a20, a21); \
      fma8(B##_1.w, t0, t1, a30, a31); } \
    { const float4 t0 = dpp4<0x101>(s0), t1 = dpp4<0x101>(s1); \
      fma8(B##_3.x, t0, t1, a00, a01); \
      fma8(B##_3.y, t0, t1, a10, a11); \
      fma8(B##_3.z, t0, t1, a20, a21); \
      fma8(B##_3.w, t0, t1, a30, a31); } \
    { const float4 t0 = dpp4<0x112>(s0), t1 = dpp4<0x112>(s1); \
      fma8(B##_0.x, t0, t1, a00, a01); \
      fma8(B##_0.y, t0, t1, a10, a11); \
      fma8(B##_0.z, t0, t1, a20, a21); \
      fma8(B##_0.w, t0, t1, a30, a31); } \
    { const float4 t0 = dpp4<0x102>(s0), t1 = dpp4<0x102>(s1); \
      fma8(B##_4.x, t0, t1, a00, a01); \
      fma8(B##_4.y, t0, t1, a10, a11); \
      fma8(B##_4.z, t0, t1, a20, a21); \
      fma8(B##_4.w, t0, t1, a30, a31); } }

    // consume b0 (even chunk), prefetch next chunk into b1 — and vice versa
#define CH_A(CB, U, POFF) \
    LOADBUF(b1, POFF) \
    CHUNK_DPP(b0, CB, U)
#define CH_B(CB, U, POFF) \
    LOADBUF(b0, POFF) \
    CHUNK_DPP(b1, CB, U)

    #pragma unroll 1
    for (int t = 0; t < TSTEPS; ++t) {
        float4 a00 = {0,0,0,0}, a01 = {0,0,0,0};
        float4 a10 = {0,0,0,0}, a11 = {0,0,0,0};
        float4 a20 = {0,0,0,0}, a21 = {0,0,0,0};
        float4 a30 = {0,0,0,0}, a31 = {0,0,0,0};

        #pragma unroll 1
        for (int g = 0; g < 4; g += 2) {    // chunk k = c*5+u at Wp f4 off k*1280
            const int cb0 = g * CROW;       // c = g
            const int cb1 = cb0 + CROW;     // c = g+1
            const int wo = g * 6400;
            const int wlast = (g == 2) ? 0 : wo + 12800;  // wrap to chunk 0

            CH_A(cb0, 0, wo + 1280)
            CH_B(cb0, 1, wo + 2560)
            CH_A(cb0, 2, wo + 3840)
            CH_B(cb0, 3, wo + 5120)
            CH_A(cb0, 4, wo + 6400)
            CH_B(cb1, 0, wo + 7680)
            CH_A(cb1, 1, wo + 8960)
            CH_B(cb1, 2, wo + 10240)
            CH_A(cb1, 3, wo + 11520)
            CH_B(cb1, 4, wlast)
        }

        a00 = lrelu4(a00); a01 = lrelu4(a01);
        a10 = lrelu4(a10); a11 = lrelu4(a11);
        a20 = lrelu4(a20); a21 = lrelu4(a21);
        a30 = lrelu4(a30); a31 = lrelu4(a31);

        if (t < TSTEPS - 1) {
            __syncthreads();   // all reads of S[t] complete before overwrite
            int c0 = 0 * CROW + pa;
            smv[c0 + swx] = a00; smv[c0 + (swx ^ 1)] = a01;
            int c1 = 1 * CROW + pa;
            smv[c1 + swx] = a10; smv[c1 + (swx ^ 1)] = a11;
            int c2 = 2 * CROW + pa;
            smv[c2 + swx] = a20; smv[c2 + (swx ^ 1)] = a21;
            int c3 = 3 * CROW + pa;
            smv[c3 + swx] = a30; smv[c3 + (swx ^ 1)] = a31;
            __syncthreads();   // writes visible before next read phase
        } else {
            float4 p0, p1;
            p0.x = (a00.x + a10.x + a20.x + a30.x) * 0.25f;
            p0.y = (a00.y + a10.y + a20.y + a30.y) * 0.25f;
            p0.z = (a00.z + a10.z + a20.z + a30.z) * 0.25f;
            p0.w = (a00.w + a10.w + a20.w + a30.w) * 0.25f;
            p1.x = (a01.x + a11.x + a21.x + a31.x) * 0.25f;
            p1.y = (a01.y + a11.y + a21.y + a31.y) * 0.25f;
            p1.z = (a01.z + a11.z + a21.z + a31.z) * 0.25f;
            p1.w = (a01.w + a11.w + a21.w + a31.w) * 0.25f;
            long ob = itemBase * 256 + tid;
            if (itemBase + 0 < batch) __builtin_nontemporal_store(p0.x, &out[ob + 0 * 256]);
            if (itemBase + 1 < batch) __builtin_nontemporal_store(p0.y, &out[ob + 1 * 256]);
            if (itemBase + 2 < batch) __builtin_nontemporal_store(p0.z, &out[ob + 2 * 256]);
            if (itemBase + 3 < batch) __builtin_nontemporal_store(p0.w, &out[ob + 3 * 256]);
            if (itemBase + 4 < batch) __builtin_nontemporal_store(p1.x, &out[ob + 4 * 256]);
            if (itemBase + 5 < batch) __builtin_nontemporal_store(p1.y, &out[ob + 5 * 256]);
            if (itemBase + 6 < batch) __builtin_nontemporal_store(p1.z, &out[ob + 6 * 256]);
            if (itemBase + 7 < batch) __builtin_nontemporal_store(p1.w, &out[ob + 7 * 256]);
        }
    }
}

extern "C" void kernel_launch(void* const* d_in, const int* in_sizes, int n_in,
                              void* d_out, int out_size, void* d_ws, size_t ws_size,
                              hipStream_t stream) {
    const float* X = (const float*)d_in[0];
    const float* W = (const float*)d_in[1];
    float* out = (float*)d_out;
    const int batch = in_sizes[0] / 784;            // 8192
    const int blocks = (batch + BPB - 1) / BPB;     // 1024

    wt_transpose<<<100, 256, 0, stream>>>(W, (float4*)d_ws);
    reservoir_kernel<<<blocks, 256, 0, stream>>>(
        X, (const float4*)d_ws, out, batch);
}